// Round 4
// baseline (247.225 us; speedup 1.0000x reference)
//
#include <hip/hip_runtime.h>
#include <hip/hip_bf16.h>
#include <cstdint>

// LSTM cell with (diagonal) peephole connections.
//   K1: cast x|hx -> bf16 A [4096][2048]; cast Wih|Whh -> bf16 W' [4096][2048]
//       with gate-interleaved row permutation n' = (h>>5)*128 + g*32 + (h&31).
//   K2: 128x128-tile bf16 MFMA GEMM, 128 threads = 2 waves, wave tile 64Mx128N
//       (acc 4x8).  PING-PONG double-buffered K-loop with BK=32:
//         prologue: stage tile 0; barrier
//         kt: issue global_load_lds for tile kt+1 into buf^1, THEN compute
//             from buf, THEN one barrier.
//       The compiler's vmcnt(0) drain before s_barrier now waits on loads
//       issued a full compute-phase earlier (warm drain) instead of the
//       serial stage->drain->compute structure of rounds 1-3.
//       Total LDS stays 32KB (2 x 16KB buffers) so 4 blocks/CU residency
//       is preserved (the m132 trap of 64KB dbuf is avoided).
//       XOR swizzle for 64B rows: chunk' = chunk ^ ((row>>1)&3) -> fragment
//       reads stay at 2-way bank aliasing (free); swizzle applied on the
//       *global source* side during staging (LDS dest must stay
//       wave-uniform-base + lane*16 per the global_load_lds rule).
//       Full LSTM epilogue fused, lane-local: gate g lives in acc[i][g*2+hh].

namespace {

constexpr int H   = 1024;   // hidden
constexpr int K2  = 2048;   // I + H
constexpr int BSZ = 4096;   // batch (M)
constexpr int BK  = 32;     // K per tile (halfwords)
constexpr int NKT = K2 / BK;  // 64 iterations
constexpr size_t OUT_CY = (size_t)BSZ * H;

typedef __attribute__((ext_vector_type(8))) short bf16x8;
typedef __attribute__((ext_vector_type(4))) float f32x4;

__device__ __forceinline__ unsigned short f2bf(float f) {
  union { float f; uint32_t u; } v; v.f = f;
  uint32_t u = v.u;
  u += 0x7FFFu + ((u >> 16) & 1u);   // round-to-nearest-even
  return (unsigned short)(u >> 16);
}

__device__ __forceinline__ float sigm(float x) {
  return 1.0f / (1.0f + __expf(-x));
}
__device__ __forceinline__ float tanh_fast(float x) {
  return 1.0f - 2.0f / (1.0f + __expf(2.0f * x));
}

__device__ __forceinline__ void gload_lds16(const void* g, void* l) {
  __builtin_amdgcn_global_load_lds(
      (const __attribute__((address_space(1))) void*)g,
      (__attribute__((address_space(3))) void*)l, 16, 0, 0);
}

}  // namespace

// ---- K1: both casts in one launch -------------------------------------------
// blocks [0, 8192): A = bf16([x|hx]); blocks [8192, 16384): W' permuted cast.
__global__ __launch_bounds__(256) void cast_kernel(
    const float* __restrict__ x, const float* __restrict__ hx,
    const float* __restrict__ wih, const float* __restrict__ whh,
    unsigned short* __restrict__ A, unsigned short* __restrict__ W) {
  int b = blockIdx.x;
  bool isW = b >= 8192;
  int t = (isW ? b - 8192 : b) * 256 + threadIdx.x;
  int idx = t * 4;
  int n = idx >> 11;
  int k = idx & 2047;
  const float* s0 = isW ? wih : x;
  const float* s1 = isW ? whh : hx;
  const float* src = (k < H) ? (s0 + (size_t)n * H + k)
                             : (s1 + (size_t)n * H + (k - H));
  float4 v = *(const float4*)src;
  ushort4 o;
  o.x = f2bf(v.x); o.y = f2bf(v.y); o.z = f2bf(v.z); o.w = f2bf(v.w);
  if (isW) {
    int g = n >> 10, h = n & 1023;
    int np = ((h >> 5) << 7) + (g << 5) + (h & 31);   // 128-wide gate groups
    *(ushort4*)(W + (size_t)np * K2 + k) = o;
  } else {
    *(ushort4*)(A + idx) = o;
  }
}

// ---- K2: fused GEMM + LSTM epilogue -----------------------------------------
// grid = (4096/128, 1024/32) = (32, 32), block = 128 (2 waves of 64Mx128N)
__global__ __launch_bounds__(128, 2) void lstm_fused_gemm(
    const unsigned short* __restrict__ A,   // [4096][2048] bf16
    const unsigned short* __restrict__ W,   // [4096][2048] bf16, permuted rows
    const float* __restrict__ cx,
    const float* __restrict__ bias_ih, const float* __restrict__ bias_hh,
    const float* __restrict__ Wpi, const float* __restrict__ Wpf,
    float* __restrict__ out) {
  // [2 buffers][128 rows][32 hw] = 2 x 8KB each array; 32KB total
  __shared__ __align__(16) unsigned short As[2][128 * BK];
  __shared__ __align__(16) unsigned short Ws[2][128 * BK];

  const int tid  = threadIdx.x;
  const int lane = tid & 63;
  const int wave = tid >> 6;          // 0,1 = M half
  const int m0 = blockIdx.x * 128;
  const int h0 = blockIdx.y * 32;
  const int w0 = blockIdx.y * 128;    // W' row base

  // --- staging geometry: 1024 chunks of 16B per (A,W) pair per kt, 8/thread.
  // chunk id cid = p*128 + tid; row = cid>>2; in-row chunk = cid&3.
  // XOR swizzle on the GLOBAL side: cg = (cid&3) ^ ((row>>1)&3).
  // Since row = p*32 + (tid>>2) and p*32>>1 = p*16 == 0 (mod 4):
  //   swizzle s = (tid>>3)&3 is p-independent.
  const int srow4 = tid >> 2;                               // row = p*32 + srow4
  const int cg8   = (((tid & 3) ^ ((tid >> 3) & 3)) << 3);  // global col (hw)

  // --- fragment geometry (16x16x32): lane reads global k-chunk = quad.
  // LDS chunk = quad ^ ((R>>1)&3); R = {wave*64|j*16} + i*16 + col, and
  // (i*16>>1)&3 == 0, so swizzle s = (col>>1)&3 is tile-independent.
  const int col  = lane & 15;
  const int quad = lane >> 4;
  const int cl8  = ((quad ^ ((col >> 1) & 3)) << 3);        // LDS col (hw)

  f32x4 acc[4][8];
#pragma unroll
  for (int i = 0; i < 4; ++i)
#pragma unroll
    for (int j = 0; j < 8; ++j)
      acc[i][j] = (f32x4){0.f, 0.f, 0.f, 0.f};

  // prologue: stage tile 0 into buffer 0
#pragma unroll
  for (int p = 0; p < 4; ++p) {
    const int row = p * 32 + srow4;
    gload_lds16(A + (size_t)(m0 + row) * K2 + cg8, &As[0][p * 1024 + tid * 8]);
    gload_lds16(W + (size_t)(w0 + row) * K2 + cg8, &Ws[0][p * 1024 + tid * 8]);
  }
  __syncthreads();

  for (int kt = 0; kt < NKT - 1; ++kt) {
    const int cur = kt & 1;
    const int nxt = cur ^ 1;
    const int kbn = (kt + 1) * BK;
    // prefetch tile kt+1 (in flight during the compute below; the vmcnt(0)
    // drain at the barrier is then warm)
#pragma unroll
    for (int p = 0; p < 4; ++p) {
      const int row = p * 32 + srow4;
      gload_lds16(A + (size_t)(m0 + row) * K2 + kbn + cg8,
                  &As[nxt][p * 1024 + tid * 8]);
      gload_lds16(W + (size_t)(w0 + row) * K2 + kbn + cg8,
                  &Ws[nxt][p * 1024 + tid * 8]);
    }
    // compute on current buffer
    {
      bf16x8 a[4], b[8];
#pragma unroll
      for (int i = 0; i < 4; ++i)
        a[i] = *(const bf16x8*)&As[cur][(wave * 64 + i * 16 + col) * BK + cl8];
#pragma unroll
      for (int j = 0; j < 8; ++j)
        b[j] = *(const bf16x8*)&Ws[cur][(j * 16 + col) * BK + cl8];
#pragma unroll
      for (int i = 0; i < 4; ++i)
#pragma unroll
        for (int j = 0; j < 8; ++j)
          acc[i][j] = __builtin_amdgcn_mfma_f32_16x16x32_bf16(a[i], b[j], acc[i][j], 0, 0, 0);
    }
    __syncthreads();
  }
  // final tile (no prefetch)
  {
    const int cur = (NKT - 1) & 1;
    bf16x8 a[4], b[8];
#pragma unroll
    for (int i = 0; i < 4; ++i)
      a[i] = *(const bf16x8*)&As[cur][(wave * 64 + i * 16 + col) * BK + cl8];
#pragma unroll
    for (int j = 0; j < 8; ++j)
      b[j] = *(const bf16x8*)&Ws[cur][(j * 16 + col) * BK + cl8];
#pragma unroll
    for (int i = 0; i < 4; ++i)
#pragma unroll
      for (int j = 0; j < 8; ++j)
        acc[i][j] = __builtin_amdgcn_mfma_f32_16x16x32_bf16(a[i], b[j], acc[i][j], 0, 0, 0);
  }

  // ---- fused LSTM epilogue ----
  // C/D layout: col = lane&15, row = quad*4 + r.
  // N-tile j: gate g = j>>1, h-half hh = j&1 -> gate g at acc[i][g*2+hh].
#pragma unroll
  for (int hh = 0; hh < 2; ++hh) {
    const int h = h0 + hh * 16 + col;
    const float bi = bias_ih[h]         + bias_hh[h];
    const float bf = bias_ih[H + h]     + bias_hh[H + h];
    const float bc = bias_ih[2 * H + h] + bias_hh[2 * H + h];
    const float bo = bias_ih[3 * H + h] + bias_hh[3 * H + h];
    const float di = Wpi[(size_t)h * (H + 1)];
    const float df = Wpf[(size_t)h * (H + 1)];
#pragma unroll
    for (int i = 0; i < 4; ++i) {
#pragma unroll
      for (int r = 0; r < 4; ++r) {
        const int m = m0 + wave * 64 + i * 16 + quad * 4 + r;
        const float c  = cx[(size_t)m * H + h];
        const float ip = acc[i][0 + hh][r] + bi;
        const float fp = acc[i][2 + hh][r] + bf;
        const float cp = acc[i][4 + hh][r] + bc;
        const float op = acc[i][6 + hh][r] + bo;
        const float ig = sigm(ip + c * di);
        const float fg = sigm(fp + c * df);
        const float cg = tanh_fast(cp);
        const float cy = fg * c + ig * cg;
        const float og = sigm(op + cy * df);   // reference reuses W_peephole_f
        const float hy = og * tanh_fast(cy);
        out[(size_t)m * H + h] = hy;
        out[OUT_CY + (size_t)m * H + h] = cy;
      }
    }
  }
}

extern "C" void kernel_launch(void* const* d_in, const int* in_sizes, int n_in,
                              void* d_out, int out_size, void* d_ws, size_t ws_size,
                              hipStream_t stream) {
  const float* x   = (const float*)d_in[0];
  const float* hx  = (const float*)d_in[1];
  const float* cx  = (const float*)d_in[2];
  const float* wih = (const float*)d_in[3];
  const float* whh = (const float*)d_in[4];
  const float* bih = (const float*)d_in[5];
  const float* bhh = (const float*)d_in[6];
  const float* wpi = (const float*)d_in[7];
  const float* wpf = (const float*)d_in[8];
  // d_in[9] (W_peephole_o) unused: reference reuses W_peephole_f for outgate.
  float* out = (float*)d_out;

  unsigned short* Abf = (unsigned short*)d_ws;
  unsigned short* Wbf = Abf + (size_t)BSZ * K2;

  cast_kernel<<<16384, 256, 0, stream>>>(x, hx, wih, whh, Abf, Wbf);

  dim3 grid(BSZ / 128, H / 32);
  lstm_fused_gemm<<<grid, 128, 0, stream>>>(Abf, Wbf, cx, bih, bhh, wpi, wpf, out);
}

// Round 5
// 231.174 us; speedup vs baseline: 1.0694x; 1.0694x over previous
//
#include <hip/hip_runtime.h>
#include <hip/hip_bf16.h>
#include <cstdint>

// LSTM cell with (diagonal) peephole connections.
//   K1: cast x|hx -> bf16 A [4096][2048]; cast Wih|Whh -> bf16 W' [4096][2048]
//       with gate-interleaved row permutation n' = (h>>5)*128 + g*32 + (h&31).
//   K2: 128x128-tile bf16 MFMA GEMM, 128 threads = 2 waves, wave tile 64Mx128N
//       (acc 4x8).  Ping-pong double-buffered K-loop, BK=32, with STATIC
//       buffer names (As0/Ws0, As1/Ws1) and the loop unrolled x2:
//       round 4's regression came from dynamic As[cur] indexing -- the
//       compiler couldn't prove the prefetch DMA doesn't alias the ds_reads
//       and inserted s_waitcnt vmcnt(0) before every compute phase.  With
//       distinct static arrays the only vmcnt(0) is the barrier drain, which
//       is now warm (prefetch issued ~300 cyc earlier, before the 12 ds_read
//       + 32 MFMA compute phase).
//       One barrier per tile: the pre-barrier lgkm/vm drain guarantees every
//       wave's frag reads from buf X are in registers before any wave's
//       post-barrier DMA overwrites buf X (WAR safe), and the same drain
//       covers the RAW on the prefetched buffer.
//       Total LDS 32KB (4 x 8KB) keeps 4 blocks/CU residency.
//       XOR swizzle for 32-hw rows (64B): chunk' = chunk ^ ((row>>1)&3);
//       applied on the *global source* side during staging (LDS dest must
//       stay wave-uniform-base + lane*16 per the global_load_lds rule);
//       fragment reads stay at 2-way bank aliasing (free).  Verified
//       conflict-free + correct in round 4.
//       Full LSTM epilogue fused, lane-local: gate g lives in acc[i][g*2+hh].

namespace {

constexpr int H   = 1024;   // hidden
constexpr int K2  = 2048;   // I + H
constexpr int BSZ = 4096;   // batch (M)
constexpr int BK  = 32;     // K per tile (halfwords)
constexpr int NKT = K2 / BK;  // 64 tiles
constexpr size_t OUT_CY = (size_t)BSZ * H;

typedef __attribute__((ext_vector_type(8))) short bf16x8;
typedef __attribute__((ext_vector_type(4))) float f32x4;

__device__ __forceinline__ unsigned short f2bf(float f) {
  union { float f; uint32_t u; } v; v.f = f;
  uint32_t u = v.u;
  u += 0x7FFFu + ((u >> 16) & 1u);   // round-to-nearest-even
  return (unsigned short)(u >> 16);
}

__device__ __forceinline__ float sigm(float x) {
  return 1.0f / (1.0f + __expf(-x));
}
__device__ __forceinline__ float tanh_fast(float x) {
  return 1.0f - 2.0f / (1.0f + __expf(2.0f * x));
}

__device__ __forceinline__ void gload_lds16(const void* g, void* l) {
  __builtin_amdgcn_global_load_lds(
      (const __attribute__((address_space(1))) void*)g,
      (__attribute__((address_space(3))) void*)l, 16, 0, 0);
}

}  // namespace

// ---- K1: both casts in one launch -------------------------------------------
// blocks [0, 8192): A = bf16([x|hx]); blocks [8192, 16384): W' permuted cast.
__global__ __launch_bounds__(256) void cast_kernel(
    const float* __restrict__ x, const float* __restrict__ hx,
    const float* __restrict__ wih, const float* __restrict__ whh,
    unsigned short* __restrict__ A, unsigned short* __restrict__ W) {
  int b = blockIdx.x;
  bool isW = b >= 8192;
  int t = (isW ? b - 8192 : b) * 256 + threadIdx.x;
  int idx = t * 4;
  int n = idx >> 11;
  int k = idx & 2047;
  const float* s0 = isW ? wih : x;
  const float* s1 = isW ? whh : hx;
  const float* src = (k < H) ? (s0 + (size_t)n * H + k)
                             : (s1 + (size_t)n * H + (k - H));
  float4 v = *(const float4*)src;
  ushort4 o;
  o.x = f2bf(v.x); o.y = f2bf(v.y); o.z = f2bf(v.z); o.w = f2bf(v.w);
  if (isW) {
    int g = n >> 10, h = n & 1023;
    int np = ((h >> 5) << 7) + (g << 5) + (h & 31);   // 128-wide gate groups
    *(ushort4*)(W + (size_t)np * K2 + k) = o;
  } else {
    *(ushort4*)(A + idx) = o;
  }
}

// ---- K2: fused GEMM + LSTM epilogue -----------------------------------------
// grid = (4096/128, 1024/32) = (32, 32), block = 128 (2 waves of 64Mx128N)
__global__ __launch_bounds__(128, 2) void lstm_fused_gemm(
    const unsigned short* __restrict__ A,   // [4096][2048] bf16
    const unsigned short* __restrict__ W,   // [4096][2048] bf16, permuted rows
    const float* __restrict__ cx,
    const float* __restrict__ bias_ih, const float* __restrict__ bias_hh,
    const float* __restrict__ Wpi, const float* __restrict__ Wpf,
    float* __restrict__ out) {
  // statically-named ping-pong buffers: 4 x 8KB = 32KB total
  __shared__ __align__(16) unsigned short As0[128 * BK];
  __shared__ __align__(16) unsigned short Ws0[128 * BK];
  __shared__ __align__(16) unsigned short As1[128 * BK];
  __shared__ __align__(16) unsigned short Ws1[128 * BK];

  const int tid  = threadIdx.x;
  const int lane = tid & 63;
  const int wave = tid >> 6;          // 0,1 = M half
  const int m0 = blockIdx.x * 128;
  const int h0 = blockIdx.y * 32;
  const int w0 = blockIdx.y * 128;    // W' row base

  // staging geometry (verified round 4): 512 chunks of 16B per tile per array,
  // 4 per thread. cid = p*128 + tid; row = p*32 + (tid>>2); global chunk is
  // XOR-swizzled: cg = (tid&3) ^ ((tid>>3)&3) (p-independent since p*16%4==0).
  const int srow4 = tid >> 2;
  const int cg8   = (((tid & 3) ^ ((tid >> 3) & 3)) << 3);  // global col (hw)

  // fragment geometry: lane wants global k-chunk = quad of row R;
  // LDS chunk = quad ^ ((R>>1)&3) = quad ^ ((col>>1)&3).
  const int col  = lane & 15;
  const int quad = lane >> 4;
  const int cl8  = ((quad ^ ((col >> 1) & 3)) << 3);        // LDS col (hw)

  f32x4 acc[4][8];
#pragma unroll
  for (int i = 0; i < 4; ++i)
#pragma unroll
    for (int j = 0; j < 8; ++j)
      acc[i][j] = (f32x4){0.f, 0.f, 0.f, 0.f};

  auto prefetch = [&](unsigned short (&AS)[128 * BK],
                      unsigned short (&WS)[128 * BK], int kb) {
#pragma unroll
    for (int p = 0; p < 4; ++p) {
      const int row = p * 32 + srow4;
      gload_lds16(A + (size_t)(m0 + row) * K2 + kb + cg8, &AS[p * 1024 + tid * 8]);
      gload_lds16(W + (size_t)(w0 + row) * K2 + kb + cg8, &WS[p * 1024 + tid * 8]);
    }
  };

  auto compute = [&](const unsigned short (&AS)[128 * BK],
                     const unsigned short (&WS)[128 * BK]) {
    bf16x8 a[4], b[8];
#pragma unroll
    for (int i = 0; i < 4; ++i)
      a[i] = *(const bf16x8*)&AS[(wave * 64 + i * 16 + col) * BK + cl8];
#pragma unroll
    for (int j = 0; j < 8; ++j)
      b[j] = *(const bf16x8*)&WS[(j * 16 + col) * BK + cl8];
#pragma unroll
    for (int i = 0; i < 4; ++i)
#pragma unroll
      for (int j = 0; j < 8; ++j)
        acc[i][j] = __builtin_amdgcn_mfma_f32_16x16x32_bf16(a[i], b[j], acc[i][j], 0, 0, 0);
  };

  // prologue: stage tile 0 into buffer 0
  prefetch(As0, Ws0, 0);
  __syncthreads();

  // unrolled x2 ping-pong: tiles 0..61 in 31 double-bodies
  for (int kt2 = 0; kt2 < (NKT - 2) / 2; ++kt2) {
    const int kb = kt2 * 2 * BK;
    prefetch(As1, Ws1, kb + BK);       // tile kt2*2+1 -> buf1
    compute(As0, Ws0);                 // tile kt2*2   (buf0)
    __syncthreads();                   // warm vmcnt drain
    prefetch(As0, Ws0, kb + 2 * BK);   // tile kt2*2+2 -> buf0
    compute(As1, Ws1);                 // tile kt2*2+1 (buf1)
    __syncthreads();
  }
  // tail: tiles 62, 63
  prefetch(As1, Ws1, (NKT - 1) * BK);  // tile 63 -> buf1
  compute(As0, Ws0);                   // tile 62
  __syncthreads();
  compute(As1, Ws1);                   // tile 63

  // ---- fused LSTM epilogue ----
  // C/D layout: col = lane&15, row = quad*4 + r.
  // N-tile j: gate g = j>>1, h-half hh = j&1 -> gate g at acc[i][g*2+hh].
#pragma unroll
  for (int hh = 0; hh < 2; ++hh) {
    const int h = h0 + hh * 16 + col;
    const float bi = bias_ih[h]         + bias_hh[h];
    const float bf = bias_ih[H + h]     + bias_hh[H + h];
    const float bc = bias_ih[2 * H + h] + bias_hh[2 * H + h];
    const float bo = bias_ih[3 * H + h] + bias_hh[3 * H + h];
    const float di = Wpi[(size_t)h * (H + 1)];
    const float df = Wpf[(size_t)h * (H + 1)];
#pragma unroll
    for (int i = 0; i < 4; ++i) {
#pragma unroll
      for (int r = 0; r < 4; ++r) {
        const int m = m0 + wave * 64 + i * 16 + quad * 4 + r;
        const float c  = cx[(size_t)m * H + h];
        const float ip = acc[i][0 + hh][r] + bi;
        const float fp = acc[i][2 + hh][r] + bf;
        const float cp = acc[i][4 + hh][r] + bc;
        const float op = acc[i][6 + hh][r] + bo;
        const float ig = sigm(ip + c * di);
        const float fg = sigm(fp + c * df);
        const float cg = tanh_fast(cp);
        const float cy = fg * c + ig * cg;
        const float og = sigm(op + cy * df);   // reference reuses W_peephole_f
        const float hy = og * tanh_fast(cy);
        out[(size_t)m * H + h] = hy;
        out[OUT_CY + (size_t)m * H + h] = cy;
      }
    }
  }
}

extern "C" void kernel_launch(void* const* d_in, const int* in_sizes, int n_in,
                              void* d_out, int out_size, void* d_ws, size_t ws_size,
                              hipStream_t stream) {
  const float* x   = (const float*)d_in[0];
  const float* hx  = (const float*)d_in[1];
  const float* cx  = (const float*)d_in[2];
  const float* wih = (const float*)d_in[3];
  const float* whh = (const float*)d_in[4];
  const float* bih = (const float*)d_in[5];
  const float* bhh = (const float*)d_in[6];
  const float* wpi = (const float*)d_in[7];
  const float* wpf = (const float*)d_in[8];
  // d_in[9] (W_peephole_o) unused: reference reuses W_peephole_f for outgate.
  float* out = (float*)d_out;

  unsigned short* Abf = (unsigned short*)d_ws;
  unsigned short* Wbf = Abf + (size_t)BSZ * K2;

  cast_kernel<<<16384, 256, 0, stream>>>(x, hx, wih, whh, Abf, Wbf);

  dim3 grid(BSZ / 128, H / 32);
  lstm_fused_gemm<<<grid, 128, 0, stream>>>(Abf, Wbf, cx, bih, bhh, wpi, wpf, out);
}

// Round 6
// 227.385 us; speedup vs baseline: 1.0873x; 1.0167x over previous
//
#include <hip/hip_runtime.h>
#include <hip/hip_bf16.h>
#include <cstdint>

// LSTM cell with (diagonal) peephole connections.
//   K1: cast x|hx -> bf16 A [4096][2048]; cast Wih|Whh -> bf16 W' [4096][2048]
//       with gate-interleaved row permutation n' = (h>>5)*128 + g*32 + (h&31)
//       (32-wide gate groups: N-tile j of 32 cols == gate j for 32 h's).
//   K2: R3's proven single-buffer 2-barrier K-loop (BK=64, 128 thr = 2 waves,
//       wave tile 64Mx128N) -- rounds 4/5 proved explicit ping-pong dbuf
//       regresses (compiler drains vmcnt at every __syncthreads regardless).
//       Changes vs R3:
//       (a) 32x32x16 MFMA instead of 16x16x32: same LDS bytes, ~17% fewer
//           matrix-pipe cycles (8.07 vs 2x4.85 cyc) and half the issue slots.
//           acc 2x4 of f32x16 = 128 VGPRs.
//       (b) XOR swizzle for 8-chunk (128B) rows: chunk' = chunk ^ (row&7),
//           applied on the *global source* side during global_load_lds
//           staging (LDS dest must stay wave-uniform-base + lane*16).
//           Fragment reads: per-16-lane phase hits 8 distinct 4-bank groups
//           x2 lanes = 2 words/bank -> conflict-free.
//       (c) XCD-aware block swizzle: flat%8 = XCD gets a contiguous band of
//           4 blockIdx.y values -> its W'-slices (4 x 512 KB) stay L2-resident,
//           so the per-kt vmcnt(0) barrier drain is served by warm L2.
//       Full LSTM epilogue fused, lane-local: gate g = acc tile j.

namespace {

constexpr int H   = 1024;   // hidden
constexpr int K2  = 2048;   // I + H
constexpr int BSZ = 4096;   // batch (M)
constexpr int BK  = 64;     // K per tile (halfwords)
constexpr int NKT = K2 / BK;  // 32 tiles
constexpr size_t OUT_CY = (size_t)BSZ * H;

typedef __attribute__((ext_vector_type(8))) short bf16x8;
typedef __attribute__((ext_vector_type(16))) float f32x16;

__device__ __forceinline__ unsigned short f2bf(float f) {
  union { float f; uint32_t u; } v; v.f = f;
  uint32_t u = v.u;
  u += 0x7FFFu + ((u >> 16) & 1u);   // round-to-nearest-even
  return (unsigned short)(u >> 16);
}

__device__ __forceinline__ float sigm(float x) {
  return 1.0f / (1.0f + __expf(-x));
}
__device__ __forceinline__ float tanh_fast(float x) {
  return 1.0f - 2.0f / (1.0f + __expf(2.0f * x));
}

__device__ __forceinline__ void gload_lds16(const void* g, void* l) {
  __builtin_amdgcn_global_load_lds(
      (const __attribute__((address_space(1))) void*)g,
      (__attribute__((address_space(3))) void*)l, 16, 0, 0);
}

}  // namespace

// ---- K1: both casts in one launch -------------------------------------------
// blocks [0, 8192): A = bf16([x|hx]); blocks [8192, 16384): W' permuted cast.
__global__ __launch_bounds__(256) void cast_kernel(
    const float* __restrict__ x, const float* __restrict__ hx,
    const float* __restrict__ wih, const float* __restrict__ whh,
    unsigned short* __restrict__ A, unsigned short* __restrict__ W) {
  int b = blockIdx.x;
  bool isW = b >= 8192;
  int t = (isW ? b - 8192 : b) * 256 + threadIdx.x;
  int idx = t * 4;
  int n = idx >> 11;
  int k = idx & 2047;
  const float* s0 = isW ? wih : x;
  const float* s1 = isW ? whh : hx;
  const float* src = (k < H) ? (s0 + (size_t)n * H + k)
                             : (s1 + (size_t)n * H + (k - H));
  float4 v = *(const float4*)src;
  ushort4 o;
  o.x = f2bf(v.x); o.y = f2bf(v.y); o.z = f2bf(v.z); o.w = f2bf(v.w);
  if (isW) {
    int g = n >> 10, h = n & 1023;
    int np = ((h >> 5) << 7) + (g << 5) + (h & 31);   // 32-wide gate groups
    *(ushort4*)(W + (size_t)np * K2 + k) = o;
  } else {
    *(ushort4*)(A + idx) = o;
  }
}

// ---- K2: fused GEMM + LSTM epilogue -----------------------------------------
// grid = (4096/128, 1024/32) = (32, 32), block = 128 (2 waves of 64Mx128N)
__global__ __launch_bounds__(128, 2) void lstm_fused_gemm(
    const unsigned short* __restrict__ A,   // [4096][2048] bf16
    const unsigned short* __restrict__ W,   // [4096][2048] bf16, permuted rows
    const float* __restrict__ cx,
    const float* __restrict__ bias_ih, const float* __restrict__ bias_hh,
    const float* __restrict__ Wpi, const float* __restrict__ Wpf,
    float* __restrict__ out) {
  __shared__ __align__(16) unsigned short As[128 * BK];   // 16 KB
  __shared__ __align__(16) unsigned short Ws[128 * BK];   // 16 KB

  const int tid  = threadIdx.x;
  const int lane = tid & 63;
  const int wave = tid >> 6;          // 0,1 = M half

  // XCD-aware remap: flat%8 ~ XCD; XCD g covers by in {4g..4g+3}, all bx.
  const int flat = blockIdx.x + 32 * blockIdx.y;
  const int xcd  = flat & 7;
  const int slot = flat >> 3;                 // 0..127
  const int bx   = slot & 31;
  const int by   = xcd * 4 + (slot >> 5);     // 0..31
  const int m0 = bx * 128;
  const int h0 = by * 32;
  const int w0 = by * 128;            // W' row base

  // staging geometry: 1024 chunks of 16B per array per kt, 8 per thread.
  // cid = p*128 + tid; row = cid>>3 = p*16 + (tid>>3); chunk = tid&7.
  // XOR swizzle on the GLOBAL side: cg = (tid&7) ^ (row&7); row&7 = (tid>>3)&7
  // (p-independent since p*16 % 8 == 0).
  const int srow  = tid >> 3;                                // row = p*16+srow
  const int cg8   = (((tid & 7) ^ ((tid >> 3) & 7)) << 3);   // global col (hw)

  // fragment geometry (32x32x16): col32 = lane&31, half = lane>>5.
  // k-step s reads global chunk c = s*2 + half of row R; LDS chunk =
  // c ^ (R&7) = c ^ (col32&7)  (tile offsets are multiples of 32).
  const int col32 = lane & 31;
  const int half  = lane >> 5;
  const int xm    = col32 & 7;

  f32x16 acc[2][4];
#pragma unroll
  for (int i = 0; i < 2; ++i)
#pragma unroll
    for (int j = 0; j < 4; ++j)
      acc[i][j] = (f32x16)(0.0f);

  for (int kt = 0; kt < NKT; ++kt) {
    const int kb = kt * BK;
    __syncthreads();                 // previous compute done before overwrite
#pragma unroll
    for (int p = 0; p < 8; ++p) {
      const int row = p * 16 + srow;
      const int ldsoff = p * 1024 + tid * 8;   // hw units; wave-uniform + lane*16B
      gload_lds16(A + (size_t)(m0 + row) * K2 + kb + cg8, &As[ldsoff]);
      gload_lds16(W + (size_t)(w0 + row) * K2 + kb + cg8, &Ws[ldsoff]);
    }
    __syncthreads();                 // drains vmcnt(0) per barrier semantics

#pragma unroll
    for (int s = 0; s < 4; ++s) {
      const int cl8 = (((s * 2 + half) ^ xm) << 3);   // LDS col (hw)
      bf16x8 a[2], b[4];
#pragma unroll
      for (int i = 0; i < 2; ++i)
        a[i] = *(const bf16x8*)&As[(wave * 64 + i * 32 + col32) * BK + cl8];
#pragma unroll
      for (int j = 0; j < 4; ++j)
        b[j] = *(const bf16x8*)&Ws[(j * 32 + col32) * BK + cl8];
#pragma unroll
      for (int i = 0; i < 2; ++i)
#pragma unroll
        for (int j = 0; j < 4; ++j)
          acc[i][j] = __builtin_amdgcn_mfma_f32_32x32x16_bf16(a[i], b[j], acc[i][j], 0, 0, 0);
    }
  }

  // ---- fused LSTM epilogue ----
  // 32x32 C/D layout: col = lane&31 (-> h), row = (r&3) + 8*(r>>2) + 4*half
  // (m74/m101-verified).  N-tile j == gate j for h = h0 + col32.
  const int h = h0 + col32;
  const float bi = bias_ih[h]         + bias_hh[h];
  const float bf = bias_ih[H + h]     + bias_hh[H + h];
  const float bc = bias_ih[2 * H + h] + bias_hh[2 * H + h];
  const float bo = bias_ih[3 * H + h] + bias_hh[3 * H + h];
  const float di = Wpi[(size_t)h * (H + 1)];
  const float df = Wpf[(size_t)h * (H + 1)];
#pragma unroll
  for (int i = 0; i < 2; ++i) {
#pragma unroll
    for (int r = 0; r < 16; ++r) {
      const int m = m0 + wave * 64 + i * 32 + (r & 3) + 8 * (r >> 2) + 4 * half;
      const float c  = cx[(size_t)m * H + h];
      const float ip = acc[i][0][r] + bi;
      const float fp = acc[i][1][r] + bf;
      const float cp = acc[i][2][r] + bc;
      const float op = acc[i][3][r] + bo;
      const float ig = sigm(ip + c * di);
      const float fg = sigm(fp + c * df);
      const float cg = tanh_fast(cp);
      const float cy = fg * c + ig * cg;
      const float og = sigm(op + cy * df);   // reference reuses W_peephole_f
      const float hy = og * tanh_fast(cy);
      out[(size_t)m * H + h] = hy;
      out[OUT_CY + (size_t)m * H + h] = cy;
    }
  }
}

extern "C" void kernel_launch(void* const* d_in, const int* in_sizes, int n_in,
                              void* d_out, int out_size, void* d_ws, size_t ws_size,
                              hipStream_t stream) {
  const float* x   = (const float*)d_in[0];
  const float* hx  = (const float*)d_in[1];
  const float* cx  = (const float*)d_in[2];
  const float* wih = (const float*)d_in[3];
  const float* whh = (const float*)d_in[4];
  const float* bih = (const float*)d_in[5];
  const float* bhh = (const float*)d_in[6];
  const float* wpi = (const float*)d_in[7];
  const float* wpf = (const float*)d_in[8];
  // d_in[9] (W_peephole_o) unused: reference reuses W_peephole_f for outgate.
  float* out = (float*)d_out;

  unsigned short* Abf = (unsigned short*)d_ws;
  unsigned short* Wbf = Abf + (size_t)BSZ * K2;

  cast_kernel<<<16384, 256, 0, stream>>>(x, hx, wih, whh, Abf, Wbf);

  dim3 grid(BSZ / 128, H / 32);
  lstm_fused_gemm<<<grid, 128, 0, stream>>>(Abf, Wbf, cx, bih, bhh, wpi, wpf, out);
}